// Round 10
// baseline (4588.441 us; speedup 1.0000x reference)
//
#include <hip/hip_runtime.h>
#include <hip/hip_cooperative_groups.h>
#include <math.h>

namespace cg = cooperative_groups;

namespace {

constexpr int kT = 30, kS = 1024, kB = 16;
constexpr int kHW = 128 * 128;
constexpr int kNF = kB * kT;                            // 480 frames
constexpr float kDT = (float)(1.0 / 29.0);
constexpr size_t kMuElems = (size_t)kB * kT * kHW * 3;  // 23,592,960 floats

__device__ __forceinline__ float splus01(float x) {
  float sp = (x > 20.0f) ? x : log1pf(expf(x));
  return fminf(fmaxf(sp, 1e-6f), 1.0f);
}

// ---------------------------------------------------------------------------
// Scatter: winner[p] = max point index s mapping to pixel p (last-write-wins
// = numpy sequential assignment). winner pre-set to -1. OOB points dropped.
// ---------------------------------------------------------------------------
__global__ void k_scatter(const float* __restrict__ vids,
                          int* __restrict__ winner) {
  const int f = blockIdx.x;
  const float* fr = vids + (size_t)f * kS * 5;
  int* wf = winner + (size_t)f * kHW;
  for (int s = threadIdx.x; s < kS; s += blockDim.x) {
    const int i = (int)(fr[s * 5 + 0] * 128.0f);
    const int j = (int)(fr[s * 5 + 1] * 128.0f);
    if ((unsigned)i < 128u && (unsigned)j < 128u)
      atomicMax(wf + i * 128 + j, s);
  }
}

// ---------------------------------------------------------------------------
// Encoder pair (unchanged, proven): conv CIN->3 relu -> 3->3. 16x32 tile.
// ---------------------------------------------------------------------------
template <int CIN, bool HAS_T>
__global__ __launch_bounds__(256, 4) void k_enc(
    const float* __restrict__ vids, const int* __restrict__ winner, int fstep,
    const float* __restrict__ w1, const float* __restrict__ b1,
    const float* __restrict__ w2, const float* __restrict__ b2,
    float* __restrict__ out) {
  __shared__ float sIn[CIN][20][36];
  __shared__ float sC1[3][18][34];

  const int tid = threadIdx.x;
  const int f = blockIdx.x >> 5;
  const int df = f * fstep;
  const int tile = blockIdx.x & 31;
  const int ty = (tile >> 2) * 16;
  const int tx = (tile & 3) * 32;

  const int* win = winner + (size_t)df * kHW;
  const float* fr = vids + (size_t)df * kS * 5;
  const float tval = HAS_T ? (float)(df % kT) * kDT : 0.0f;

  for (int pix = tid; pix < 20 * 36; pix += 256) {
    const int r = pix / 36, c = pix - r * 36;
    const int gy = ty - 2 + r, gx = tx - 2 + c;
    const bool inb = ((unsigned)gy < 128u) && ((unsigned)gx < 128u);
    int wn = -1;
    if (inb) wn = win[gy * 128 + gx];
    float y0 = 0.0f, y1 = 0.0f, y2 = 0.0f;
    if (wn >= 0) {
      y0 = fminf(fmaxf(fr[wn * 5 + 2], 0.0f), 1.0f);
      y1 = fminf(fmaxf(fr[wn * 5 + 3], 0.0f), 1.0f);
      y2 = fminf(fmaxf(fr[wn * 5 + 4], 0.0f), 1.0f);
    }
    sIn[0][r][c] = y0;
    sIn[1][r][c] = y1;
    sIn[2][r][c] = y2;
    if (HAS_T) sIn[3][r][c] = inb ? tval : 0.0f;
    sIn[CIN - 1][r][c] = (wn >= 0) ? 1.0f : 0.0f;
  }
  __syncthreads();

  for (int pos = tid; pos < 18 * 34; pos += 256) {
    const int r = pos / 34, c = pos - (pos / 34) * 34;
    const int gy = ty - 1 + r, gx = tx - 1 + c;
    float a0 = b1[0], a1 = b1[1], a2 = b1[2];
#pragma unroll
    for (int ic = 0; ic < CIN; ic++)
#pragma unroll
      for (int k = 0; k < 9; k++) {
        const float v = sIn[ic][r + k / 3][c + k % 3];
        a0 = fmaf(v, w1[(0 * CIN + ic) * 9 + k], a0);
        a1 = fmaf(v, w1[(1 * CIN + ic) * 9 + k], a1);
        a2 = fmaf(v, w1[(2 * CIN + ic) * 9 + k], a2);
      }
    const bool inb = ((unsigned)gy < 128u) && ((unsigned)gx < 128u);
    sC1[0][r][c] = inb ? fmaxf(a0, 0.0f) : 0.0f;
    sC1[1][r][c] = inb ? fmaxf(a1, 0.0f) : 0.0f;
    sC1[2][r][c] = inb ? fmaxf(a2, 0.0f) : 0.0f;
  }
  __syncthreads();

  float* of = out + (size_t)f * 3 * kHW;
  for (int pos = tid; pos < 512; pos += 256) {
    const int r = pos >> 5, c = pos & 31;
    float a0 = b2[0], a1 = b2[1], a2 = b2[2];
#pragma unroll
    for (int ic = 0; ic < 3; ic++)
#pragma unroll
      for (int k = 0; k < 9; k++) {
        const float v = sC1[ic][r + k / 3][c + k % 3];
        a0 = fmaf(v, w2[(0 * 3 + ic) * 9 + k], a0);
        a1 = fmaf(v, w2[(1 * 3 + ic) * 9 + k], a1);
        a2 = fmaf(v, w2[(2 * 3 + ic) * 9 + k], a2);
      }
    const int p = (ty + r) * 128 + (tx + c);
    of[p] = a0;
    of[kHW + p] = a1;
    of[2 * kHW + p] = a2;
  }
}

// ---------------------------------------------------------------------------
// Init decode (unchanged, proven).
// ---------------------------------------------------------------------------
__global__ __launch_bounds__(256, 4) void k_dec_init(
    const float* __restrict__ h,
    const float* __restrict__ w1, const float* __restrict__ b1,
    const float* __restrict__ w2, const float* __restrict__ b2,
    float* __restrict__ out) {
  __shared__ float sIn[3][20][20];
  __shared__ float sA[12][18][18];

  const int tid = threadIdx.x;
  const int bb = blockIdx.x >> 6;
  const int tile = blockIdx.x & 63;
  const int ty = (tile >> 3) * 16, tx = (tile & 7) * 16;

  const float* sf = h + (size_t)bb * 3 * kHW;
  for (int idx = tid; idx < 3 * 400; idx += 256) {
    const int ch = idx / 400, rem = idx - ch * 400;
    const int r = rem / 20, c = rem - r * 20;
    const int gy = ty - 2 + r, gx = tx - 2 + c;
    float v = 0.0f;
    if ((unsigned)gy < 128u && (unsigned)gx < 128u)
      v = sf[ch * kHW + gy * 128 + gx];
    sIn[ch][r][c] = v;
  }
  __syncthreads();

  const int r = tid >> 4, c = tid & 15;
  float ft[6];
#pragma unroll
  for (int oc = 0; oc < 6; oc++) ft[oc] = b2[oc];

  for (int pass = 0; pass < 2; ++pass) {
    for (int pos = tid; pos < 18 * 18; pos += 256) {
      const int pr = pos / 18, pc = pos - (pos / 18) * 18;
      const int gy = ty - 1 + pr, gx = tx - 1 + pc;
      const bool inb = ((unsigned)gy < 128u) && ((unsigned)gx < 128u);
      float gv[27];
#pragma unroll
      for (int ic = 0; ic < 3; ic++)
#pragma unroll
        for (int k = 0; k < 9; k++)
          gv[ic * 9 + k] = sIn[ic][pr + k / 3][pc + k % 3];
      for (int ol = 0; ol < 12; ol++) {
        const int oc = pass * 12 + ol;
        float acc = b1[oc];
#pragma unroll
        for (int q = 0; q < 27; q++) acc = fmaf(gv[q], w1[oc * 27 + q], acc);
        sA[ol][pr][pc] = inb ? fmaxf(acc, 0.0f) : 0.0f;
      }
    }
    __syncthreads();

    for (int il = 0; il < 12; il++) {
      const int ic = pass * 12 + il;
      float av[9];
#pragma unroll
      for (int k = 0; k < 9; k++) av[k] = sA[il][r + k / 3][c + k % 3];
#pragma unroll
      for (int oc = 0; oc < 6; oc++)
#pragma unroll
        for (int k = 0; k < 9; k++)
          ft[oc] = fmaf(av[k], w2[(oc * 24 + ic) * 9 + k], ft[oc]);
    }
    __syncthreads();
  }

  {
    const int p = (ty + r) * 128 + (tx + c);
    const size_t ob = ((size_t)(bb * kT + 0) * kHW + p) * 3;
#pragma unroll
    for (int ch = 0; ch < 3; ch++) {
      out[ob + ch] = ft[ch];
      out[kMuElems + ob + ch] = splus01(ft[3 + ch]);
    }
  }
}

// ---------------------------------------------------------------------------
// Recurrent cell, persistent-capable. Runs steps t in [tStart, tEnd) with a
// grid.sync() between consecutive steps (only reachable when tEnd > tStart+1,
// i.e. the cooperative launch). Each block serially processes
// tilesPer = 2048/gridDim.x of the 2048 (b, 8x16-tile) work items per step,
// so the cooperative grid can be sized to whatever the runtime guarantees
// co-resident. Fallback: 29 normal launches with (t, t+1) — no sync executed.
// ---------------------------------------------------------------------------
__global__ __launch_bounds__(128, 4) void k_cell_persist(
    const float* __restrict__ E,
    const float* __restrict__ mgw, const float* __restrict__ mgb,
    const float* __restrict__ cw1, const float* __restrict__ cb1,
    const float* __restrict__ cw2, const float* __restrict__ cb2,
    float* __restrict__ out, int tStart, int tEnd) {
  cg::grid_group grid = cg::this_grid();

  __shared__ float sIn[6][14][22];   // 7.2 KB
  __shared__ float sG[3][12][20];    // 2.8 KB
  __shared__ float sA[12][10][18];   // 8.4 KB

  const int tid = threadIdx.x;
  const int tilesPer = 2048 / gridDim.x;
  const int r = tid >> 4, c = tid & 15;  // thread's pixel in the 8x16 tile

  for (int t = tStart; t < tEnd; ++t) {
    if (t > tStart) grid.sync();  // out[t-1] complete before staging reads

    for (int sub = 0; sub < tilesPer; ++sub) {
      const int gtile = blockIdx.x * tilesPer + sub;
      const int bb = gtile >> 7;
      const int tile = gtile & 127;
      const int ty = (tile >> 3) * 8;
      const int tx = (tile & 7) * 16;

      const float* Ep = E + (size_t)(bb * kT + t - 1) * 3 * kHW;
      const float* Ec = Ep + 3 * kHW;
      const float* prevMu = out + (size_t)(bb * kT + (t - 1)) * kHW * 3;

      // Stage 6 x 14x22 (3-halo): prev mu + inline hc = (E[t-1]-E[t])/Dt.
      for (int pix = tid; pix < 14 * 22; pix += 128) {
        const int rr = pix / 22, cc = pix - rr * 22;
        const int gy = ty - 3 + rr, gx = tx - 3 + cc;
        float m0 = 0.0f, m1 = 0.0f, m2 = 0.0f;
        float h0 = 0.0f, h1 = 0.0f, h2 = 0.0f;
        if ((unsigned)gy < 128u && (unsigned)gx < 128u) {
          const int p = gy * 128 + gx;
          m0 = prevMu[p * 3 + 0];
          m1 = prevMu[p * 3 + 1];
          m2 = prevMu[p * 3 + 2];
          h0 = (Ep[0 * kHW + p] - Ec[0 * kHW + p]) / kDT;
          h1 = (Ep[1 * kHW + p] - Ec[1 * kHW + p]) / kDT;
          h2 = (Ep[2 * kHW + p] - Ec[2 * kHW + p]) / kDT;
        }
        sIn[0][rr][cc] = m0;
        sIn[1][rr][cc] = m1;
        sIn[2][rr][cc] = m2;
        sIn[3][rr][cc] = h0;
        sIn[4][rr][cc] = h1;
        sIn[5][rr][cc] = h2;
      }
      __syncthreads();

      // sG = conv(sIn, mg) + bias (no relu), 12x20, zero outside image.
      for (int pos = tid; pos < 12 * 20; pos += 128) {
        const int rr = pos / 20, cc = pos - (pos / 20) * 20;
        const int gy = ty - 2 + rr, gx = tx - 2 + cc;
        float a0 = mgb[0], a1 = mgb[1], a2 = mgb[2];
#pragma unroll
        for (int ic = 0; ic < 6; ic++)
#pragma unroll
          for (int k = 0; k < 9; k++) {
            const float v = sIn[ic][rr + k / 3][cc + k % 3];
            a0 = fmaf(v, mgw[(0 * 6 + ic) * 9 + k], a0);
            a1 = fmaf(v, mgw[(1 * 6 + ic) * 9 + k], a1);
            a2 = fmaf(v, mgw[(2 * 6 + ic) * 9 + k], a2);
          }
        const bool inb = ((unsigned)gy < 128u) && ((unsigned)gx < 128u);
        sG[0][rr][cc] = inb ? a0 : 0.0f;
        sG[1][rr][cc] = inb ? a1 : 0.0f;
        sG[2][rr][cc] = inb ? a2 : 0.0f;
      }
      __syncthreads();

      float ft[6];
#pragma unroll
      for (int oc = 0; oc < 6; oc++) ft[oc] = cb2[oc];

      for (int pass = 0; pass < 2; ++pass) {
        for (int pos = tid; pos < 10 * 18; pos += 128) {
          const int pr = pos / 18, pc = pos - (pos / 18) * 18;
          const int gy = ty - 1 + pr, gx = tx - 1 + pc;
          const bool inb = ((unsigned)gy < 128u) && ((unsigned)gx < 128u);
          float gv[27];
#pragma unroll
          for (int ic = 0; ic < 3; ic++)
#pragma unroll
            for (int k = 0; k < 9; k++)
              gv[ic * 9 + k] = sG[ic][pr + k / 3][pc + k % 3];
          for (int ol = 0; ol < 12; ol++) {
            const int oc = pass * 12 + ol;
            float acc = cb1[oc];
#pragma unroll
            for (int q = 0; q < 27; q++)
              acc = fmaf(gv[q], cw1[oc * 27 + q], acc);
            sA[ol][pr][pc] = inb ? fmaxf(acc, 0.0f) : 0.0f;
          }
        }
        __syncthreads();

        for (int il = 0; il < 12; il++) {
          const int ic = pass * 12 + il;
          float av[9];
#pragma unroll
          for (int k = 0; k < 9; k++) av[k] = sA[il][r + k / 3][c + k % 3];
#pragma unroll
          for (int oc = 0; oc < 6; oc++)
#pragma unroll
            for (int k = 0; k < 9; k++)
              ft[oc] = fmaf(av[k], cw2[(oc * 24 + ic) * 9 + k], ft[oc]);
        }
        __syncthreads();
      }

      {
        const int p = (ty + r) * 128 + (tx + c);
        const size_t ob = ((size_t)(bb * kT + t) * kHW + p) * 3;
#pragma unroll
        for (int ch = 0; ch < 3; ch++) {
          out[ob + ch] = ft[ch] * kDT;
          out[kMuElems + ob + ch] = splus01(ft[3 + ch] * kDT);
        }
      }
    }
  }
}

}  // namespace

extern "C" void kernel_launch(void* const* d_in, const int* in_sizes, int n_in,
                              void* d_out, int out_size, void* d_ws,
                              size_t ws_size, hipStream_t stream) {
  const float* vids  = (const float*)d_in[0];
  const float* ie_w1 = (const float*)d_in[1];
  const float* ie_b1 = (const float*)d_in[2];
  const float* ie_w2 = (const float*)d_in[3];
  const float* ie_b2 = (const float*)d_in[4];
  const float* id_w1 = (const float*)d_in[5];
  const float* id_b1 = (const float*)d_in[6];
  const float* id_w2 = (const float*)d_in[7];
  const float* id_b2 = (const float*)d_in[8];
  const float* ce_w1 = (const float*)d_in[9];
  const float* ce_b1 = (const float*)d_in[10];
  const float* ce_w2 = (const float*)d_in[11];
  const float* ce_b2 = (const float*)d_in[12];
  const float* cd_w1 = (const float*)d_in[13];
  const float* cd_b1 = (const float*)d_in[14];
  const float* cd_w2 = (const float*)d_in[15];
  const float* cd_b2 = (const float*)d_in[16];
  const float* mg_w  = (const float*)d_in[17];
  const float* mg_b  = (const float*)d_in[18];

  char* ws = (char*)d_ws;
  int* winner = (int*)ws;   ws += (size_t)kNF * kHW * 4;       // 31.5 MB
  float* h    = (float*)ws; ws += (size_t)kB * 3 * kHW * 4;    // 3.1 MB
  float* E    = (float*)ws; ws += (size_t)kNF * 3 * kHW * 4;   // 94.4 MB

  float* out = (float*)d_out;  // float32 (reference output dtype)

  hipMemsetAsync(winner, 0xFF, (size_t)kNF * kHW * 4, stream);
  k_scatter<<<kNF, 256, 0, stream>>>(vids, winner);

  // E[b,t] = enc2(vid_t[b,t]) for all 480 frames (parallel, 32 tiles each).
  k_enc<5, true><<<kNF * 32, 256, 0, stream>>>(vids, winner, 1, ce_w1, ce_b1,
                                               ce_w2, ce_b2, E);
  // h[b] = init encoder on frame (b, 0).
  k_enc<4, false><<<kB * 32, 256, 0, stream>>>(vids, winner, kT, ie_w1, ie_b1,
                                               ie_w2, ie_b2, h);
  // init decode: t=0 outputs (mu0 doubles as recurrent state in `out`).
  k_dec_init<<<kB * 64, 256, 0, stream>>>(h, id_w1, id_b1, id_w2, id_b2, out);

  // Recurrence: cooperative if the runtime guarantees co-residency; else
  // fall back to 29 per-step launches of the SAME kernel (no grid.sync).
  int maxBlk = 0;
  (void)hipOccupancyMaxActiveBlocksPerMultiprocessor(
      &maxBlk, (const void*)k_cell_persist, 128, 0);

  int grid = 0;
  if (maxBlk >= 8) grid = 2048;
  else if (maxBlk >= 4) grid = 1024;
  else if (maxBlk >= 2) grid = 512;
  else if (maxBlk >= 1) grid = 256;

  hipError_t ce = hipErrorUnknown;
  if (grid > 0) {
    int t1 = 1, tE = kT;
    void* args[] = {(void*)&E,     (void*)&mg_w,  (void*)&mg_b,
                    (void*)&cd_w1, (void*)&cd_b1, (void*)&cd_w2,
                    (void*)&cd_b2, (void*)&out,   (void*)&t1, (void*)&tE};
    ce = hipLaunchCooperativeKernel((const void*)k_cell_persist, dim3(grid),
                                    dim3(128), args, 0, stream);
  }
  if (ce != hipSuccess) {
    (void)hipGetLastError();  // clear sticky error; use fallback path
    for (int t = 1; t < kT; ++t) {
      k_cell_persist<<<2048, 128, 0, stream>>>(E, mg_w, mg_b, cd_w1, cd_b1,
                                               cd_w2, cd_b2, out, t, t + 1);
    }
  }
}